// Round 23
// baseline (1815.777 us; speedup 1.0000x reference)
//
#include <hip/hip_runtime.h>
#include <math.h>

#define NB 4
#define NP 2048
#define KNN 40
#define BEPS 1e-5f
#define NSLOT 64
#define CMCH 16

typedef unsigned long long u64;

static __device__ __forceinline__ float leaky(float x) { return x >= 0.f ? x : 0.2f * x; }

// key: fp32 value (order-preserving bijection to u32) + lower-index tie-break
static __device__ __forceinline__ u64 keyOf(float v, int m) {
  unsigned u = __float_as_uint(v);
  u ^= (u >> 31) ? 0xFFFFFFFFu : 0x80000000u;
  return ((u64)u << 32) | (unsigned)(NP - 1 - m);
}
static __device__ __forceinline__ u64 umax64(u64 a, u64 b) { return a > b ? a : b; }

// ---------------- parallel-quarter top-40: 4 queries/block, each 64-thread group selects one query ----------------
// pd[4][NP] in LDS. Threads h*64..h*64+63 own query h. Every handoff crosses a block barrier.
// Bit-identical per query: argmax over total-order key (value||index) is partition-independent.
static __device__ __forceinline__ void select40_quad(float (*pd)[NP], int* __restrict__ outp,
                                                     int tid, u64* red, u64* red2, int* sh_w) {
  int h = tid >> 6, t = tid & 63;
  u64 myBest = 0;
  #pragma unroll
  for (int j = 0; j < 32; ++j) myBest = umax64(myBest, keyOf(pd[h][t + j*64], t + j*64));
  for (int kk = 0; kk < KNN; ++kk) {
    red[tid] = myBest;
    __syncthreads();
    if (t < 8) {
      u64 v = red[h*64 + t];
      #pragma unroll
      for (int j = 1; j < 8; ++j) v = umax64(v, red[h*64 + t + j*8]);
      red2[h*8 + t] = v;
    }
    __syncthreads();
    if (t == 0) {
      u64 v = red2[h*8];
      #pragma unroll
      for (int j = 1; j < 8; ++j) v = umax64(v, red2[h*8 + j]);
      int w = NP - 1 - (int)(v & 0xFFFFFFFFu);
      outp[h*KNN + kk] = w;
      pd[h][w] = -INFINITY;
      sh_w[h] = w;
    }
    __syncthreads();
    if ((sh_w[h] & 63) == t) {
      u64 nb = 0;
      #pragma unroll
      for (int j = 0; j < 32; ++j) nb = umax64(nb, keyOf(pd[h][t + j*64], t + j*64));
      myBest = nb;
    }
  }
}

// ---------------- canary ----------------
__global__ __launch_bounds__(256) void canary_kernel(float* __restrict__ out, int n, float val) {
  int i = blockIdx.x*256 + threadIdx.x;
  if (i < n) out[i] = val;
}

// ---------------- knn for C=3 — 4 queries/block, shared x rows, parallel-quarter select ----------------
__global__ __launch_bounds__(256) void knn3_kernel(const float* __restrict__ x, int* __restrict__ idx) {
  int b = blockIdx.y, n0 = blockIdx.x*4, tid = threadIdx.x;
  __shared__ float pd[4][NP];
  __shared__ float xq[4][3];
  __shared__ float xxq[4];
  __shared__ u64 red[256];
  __shared__ u64 red2[32];
  __shared__ int sh_w[4];
  if (tid < 4) {
    int n = n0 + tid;
    float a0 = x[(b*3+0)*NP+n], a1 = x[(b*3+1)*NP+n], a2 = x[(b*3+2)*NP+n];
    xq[tid][0] = a0; xq[tid][1] = a1; xq[tid][2] = a2;
    xxq[tid] = __fadd_rn(__fadd_rn(__fmul_rn(a0,a0), __fmul_rn(a1,a1)), __fmul_rn(a2,a2));
  }
  __syncthreads();
  for (int m = tid; m < NP; m += 256) {
    float m0 = x[(b*3+0)*NP+m], m1 = x[(b*3+1)*NP+m], m2 = x[(b*3+2)*NP+m];
    float xxm = __fadd_rn(__fadd_rn(__fmul_rn(m0,m0), __fmul_rn(m1,m1)), __fmul_rn(m2,m2));
    #pragma unroll
    for (int q = 0; q < 4; ++q) {
      float dot = __fmaf_rn(xq[q][2], m2, __fmaf_rn(xq[q][1], m1, __fmul_rn(xq[q][0], m0)));
      float inner = __fmul_rn(-2.f, dot);
      pd[q][m] = __fsub_rn(__fsub_rn(-xxm, inner), xxq[q]);
    }
  }
  __syncthreads();
  select40_quad(pd, &idx[((size_t)b*NP + n0)*KNN], tid, red, red2, sh_w);
}

// ---------------- xx for 64-channel rc — sequential no-FMA (XLA reduce) ----------------
__global__ __launch_bounds__(256) void xx64_kernel(const float* __restrict__ rc, float* __restrict__ xx) {
  int i = blockIdx.x*256 + threadIdx.x;
  if (i >= NB*NP) return;
  const float* p = &rc[(size_t)i*64];
  float s = __fmul_rn(p[0], p[0]);
  #pragma unroll
  for (int c = 1; c < 64; ++c) s = __fadd_rn(s, __fmul_rn(p[c], p[c]));
  xx[i] = s;
}

// ---------------- knn for C=64 — 4 queries/block shared-row dot + parallel-quarter select ----------------
__global__ __launch_bounds__(256) void knn64_kernel(const float* __restrict__ rc, const float* __restrict__ xx,
                                                    int* __restrict__ idx) {
  int b = blockIdx.y, n0 = blockIdx.x*4, tid = threadIdx.x;
  __shared__ float pd[4][NP];
  __shared__ float xn[4][64];
  __shared__ u64 red[256];
  __shared__ u64 red2[32];
  __shared__ int sh_w[4];
  xn[tid >> 6][tid & 63] = rc[((size_t)b*NP + n0 + (tid >> 6))*64 + (tid & 63)];
  __syncthreads();
  float xxn0 = xx[b*NP + n0], xxn1 = xx[b*NP + n0 + 1];
  float xxn2 = xx[b*NP + n0 + 2], xxn3 = xx[b*NP + n0 + 3];
  for (int m = tid; m < NP; m += 256) {
    const float* xm = &rc[((size_t)b*NP + m)*64];
    float v0 = xm[0];
    float d0 = __fmul_rn(xn[0][0], v0);
    float d1 = __fmul_rn(xn[1][0], v0);
    float d2 = __fmul_rn(xn[2][0], v0);
    float d3 = __fmul_rn(xn[3][0], v0);
    #pragma unroll
    for (int c = 1; c < 64; ++c) {
      float v = xm[c];
      d0 = __fmaf_rn(xn[0][c], v, d0);
      d1 = __fmaf_rn(xn[1][c], v, d1);
      d2 = __fmaf_rn(xn[2][c], v, d2);
      d3 = __fmaf_rn(xn[3][c], v, d3);
    }
    float xxm = xx[b*NP + m];
    pd[0][m] = __fsub_rn(__fsub_rn(-xxm, __fmul_rn(-2.f, d0)), xxn0);
    pd[1][m] = __fsub_rn(__fsub_rn(-xxm, __fmul_rn(-2.f, d1)), xxn1);
    pd[2][m] = __fsub_rn(__fsub_rn(-xxm, __fmul_rn(-2.f, d2)), xxn2);
    pd[3][m] = __fsub_rn(__fsub_rn(-xxm, __fmul_rn(-2.f, d3)), xxn3);
  }
  __syncthreads();
  select40_quad(pd, &idx[((size_t)b*NP + n0)*KNN], tid, red, red2, sh_w);
}

// ================= FAST PATH: single-compute passes via global y buffer =================

// ---- s1a: gc1(46) + W3 -> y raw + stats3 (UNCHANGED — feeds rc, discrete path) ----
__global__ __launch_bounds__(256) void s1a_kernel(
    const float* __restrict__ x, const int* __restrict__ idx1, const float* __restrict__ W3,
    double* __restrict__ stslots, float* __restrict__ y)
{
  int b = blockIdx.y, n = blockIdx.x, tid = threadIdx.x;
  __shared__ int sidx[4][KNN];
  __shared__ float rs[KNN][4];
  __shared__ float ns[KNN][4];
  __shared__ float scale[3];
  __shared__ __align__(16) float feat[KNN*48];
  __shared__ float w3s[64*48];
  __shared__ double sred[4][64];

  for (int i = tid; i < 4*KNN; i += 256) sidx[i/KNN][i%KNN] = idx1[((i/KNN)*NP + n)*KNN + (i%KNN)];
  for (int i = tid; i < 64*48; i += 256) { int o = i/48, ci = i%48; w3s[i] = (ci < 46) ? W3[o*46+ci] : 0.f; }
  __syncthreads();
  for (int i = tid; i < KNN*3; i += 256) {
    int k = i/3, c = i%3;
    float ctr = x[(b*3+c)*NP + n];
    float r = x[(b*3+c)*NP + sidx[b][k]] - ctr;
    float s = 0.f;
    for (int b2 = 0; b2 < 4; ++b2) s += x[(b2*3+c)*NP + sidx[b2][k]] - x[(b2*3+c)*NP + n];
    rs[k][c] = r; ns[k][c] = r - 0.25f*s;
  }
  __syncthreads();
  if (tid < 3) {
    float s = 0.f; for (int k = 0; k < KNN; ++k) s += rs[k][tid];
    float m = s/(float)KNN; float v = 0.f;
    for (int k = 0; k < KNN; ++k) { float d = rs[k][tid]-m; v += d*d; }
    scale[tid] = 1.f - v/(float)(KNN-1);
  }
  __syncthreads();
  for (int i = tid; i < KNN*48; i += 256) {
    int k = i/48, ci = i%48; float v;
    if (ci < 3) v = x[(b*3+ci)*NP+n];
    else if (ci < 6) v = rs[k][ci-3]*scale[ci-3];
    else if (ci < 46) { int j = ci-6; v = rs[k][0]*ns[j][0] + rs[k][1]*ns[j][1] + rs[k][2]*ns[j][2]; }
    else v = 0.f;
    feat[i] = v;
  }
  __syncthreads();

  int o = tid & 63, kg = tid >> 6;
  float acc[10];
  #pragma unroll
  for (int t = 0; t < 10; ++t) acc[t] = 0.f;
  for (int ci4 = 0; ci4 < 12; ++ci4) {
    float w0 = w3s[o*48+ci4*4+0], w1 = w3s[o*48+ci4*4+1], w2 = w3s[o*48+ci4*4+2], w3c = w3s[o*48+ci4*4+3];
    #pragma unroll
    for (int t = 0; t < 10; ++t) {
      float4 f4 = *(const float4*)&feat[(kg*10+t)*48 + ci4*4];
      acc[t] += f4.x*w0 + f4.y*w1 + f4.z*w2 + f4.w*w3c;
    }
  }
  size_t bn40 = (size_t)(b*NP+n)*KNN;
  #pragma unroll
  for (int t = 0; t < 10; ++t) y[(bn40 + kg*10+t)*64 + o] = acc[t];
  double s = 0.0, s2 = 0.0;
  #pragma unroll
  for (int t = 0; t < 10; ++t) { double a = acc[t]; s += a; s2 += a*a; }
  int slot = (blockIdx.y*NP + blockIdx.x) & (NSLOT-1);
  sred[kg][o] = s; __syncthreads();
  if (kg == 0) atomicAdd(&stslots[slot*128 + o], sred[0][o]+sred[1][o]+sred[2][o]+sred[3][o]);
  __syncthreads();
  sred[kg][o] = s2; __syncthreads();
  if (kg == 0) atomicAdd(&stslots[slot*128 + 64 + o], sred[0][o]+sred[1][o]+sred[2][o]+sred[3][o]);
}

// ---- s2a: gc2(168) + W5 -> y raw + stats5, REASSOCIATED: u[o][c] folds scale+cov terms ----
__global__ __launch_bounds__(256) void s2a_kernel(
    const float* __restrict__ rc, const int* __restrict__ idx2, const float* __restrict__ W5,
    double* __restrict__ stslots, float* __restrict__ y)
{
  int b = blockIdx.y, n = blockIdx.x, tid = threadIdx.x;
  __shared__ int sidx[4][KNN];
  __shared__ float rsT[64*41];
  __shared__ float nsT[64*41];
  __shared__ float scale[64];
  __shared__ float u[64*65];
  __shared__ float acc0s[64];
  __shared__ double sred[4][64];

  for (int i = tid; i < 4*KNN; i += 256) sidx[i/KNN][i%KNN] = idx2[((i/KNN)*NP + n)*KNN + (i%KNN)];
  __syncthreads();
  for (int i = tid; i < KNN*64; i += 256) {
    int k = i >> 6, c = i & 63;
    float ctr = rc[((size_t)(b*NP+n))*64 + c];
    float r = rc[((size_t)(b*NP) + sidx[b][k])*64 + c] - ctr;
    float s = 0.f;
    for (int b2 = 0; b2 < 4; ++b2)
      s += rc[((size_t)(b2*NP) + sidx[b2][k])*64 + c] - rc[((size_t)(b2*NP+n))*64 + c];
    rsT[c*41+k] = r; nsT[c*41+k] = r - 0.25f*s;
  }
  __syncthreads();
  if (tid < 64) {
    int c = tid;
    float s = 0.f; for (int k = 0; k < KNN; ++k) s += rsT[c*41+k];
    float m = s/(float)KNN; float v = 0.f;
    for (int k = 0; k < KNN; ++k) { float d = rsT[c*41+k]-m; v += d*d; }
    scale[c] = 1.f - v/(float)(KNN-1);
  }
  __syncthreads();
  for (int i = tid; i < 64*64; i += 256) {
    int o = i >> 6, c = i & 63;
    const float* wr = &W5[(size_t)o*168];
    float a = __fmul_rn(wr[64+c], scale[c]);
    #pragma unroll 8
    for (int j = 0; j < KNN; ++j) a = __fmaf_rn(wr[128+j], nsT[c*41+j], a);
    u[o*65+c] = a;
  }
  if (tid < 64) {
    int o = tid;
    const float* wr = &W5[(size_t)o*168];
    const float* xc = &rc[((size_t)(b*NP+n))*64];
    float a = 0.f;
    for (int c = 0; c < 64; ++c) a = __fmaf_rn(wr[c], xc[c], a);
    acc0s[o] = a;
  }
  __syncthreads();

  int o = tid & 63, kg = tid >> 6;
  float acc[10];
  #pragma unroll
  for (int t = 0; t < 10; ++t) acc[t] = acc0s[o];
  for (int c = 0; c < 64; ++c) {
    float uoc = u[o*65+c];
    const float* rsc = &rsT[c*41 + kg*10];
    #pragma unroll
    for (int t = 0; t < 10; ++t) acc[t] = __fmaf_rn(rsc[t], uoc, acc[t]);
  }
  size_t bn40 = (size_t)(b*NP+n)*KNN;
  #pragma unroll
  for (int t = 0; t < 10; ++t) y[(bn40 + kg*10+t)*64 + o] = acc[t];
  double s = 0.0, s2 = 0.0;
  #pragma unroll
  for (int t = 0; t < 10; ++t) { double a = acc[t]; s += a; s2 += a*a; }
  int slot = (blockIdx.y*NP + blockIdx.x) & (NSLOT-1);
  sred[kg][o] = s; __syncthreads();
  if (kg == 0) atomicAdd(&stslots[slot*128 + o], sred[0][o]+sred[1][o]+sred[2][o]+sred[3][o]);
  __syncthreads();
  sred[kg][o] = s2; __syncthreads();
  if (kg == 0) atomicAdd(&stslots[slot*128 + 64 + o], sred[0][o]+sred[1][o]+sred[2][o]+sred[3][o]);
}

// ---- mid: y(raw) -> bn(st_prev)+leaky -> 64x64 GEMM W -> y (in-place) + stats ----
__global__ __launch_bounds__(256) void mid_kernel(
    float* __restrict__ y, const float* __restrict__ W,
    const double* __restrict__ stp, const float* __restrict__ gv, const float* __restrict__ bv,
    double* __restrict__ stslots)
{
  int b = blockIdx.y, n = blockIdx.x, tid = threadIdx.x;
  __shared__ float m_s[64], sc_s[64], bo_s[64];
  __shared__ __align__(16) float ytile[KNN*68];
  __shared__ double sred[4][64];
  const double INV_M1 = 1.0/327680.0;

  if (tid < 64) {
    double md = stp[tid]*INV_M1;
    double vd = stp[64+tid]*INV_M1 - md*md;
    m_s[tid] = (float)md;
    sc_s[tid] = gv[tid]/sqrtf((float)vd + BEPS);
    bo_s[tid] = bv[tid];
  }
  __syncthreads();
  size_t bn40 = (size_t)(b*NP+n)*KNN;
  for (int i = tid; i < KNN*64; i += 256) {
    int k = i >> 6, c = i & 63;
    float v = y[(bn40 + k)*64 + c];
    ytile[k*68+c] = leaky(sc_s[c]*(v - m_s[c]) + bo_s[c]);
  }
  __syncthreads();
  int o = tid & 63, kg = tid >> 6;
  float acc2[10];
  #pragma unroll
  for (int t = 0; t < 10; ++t) acc2[t] = 0.f;
  for (int c4 = 0; c4 < 16; ++c4) {
    float4 wv = *(const float4*)&W[(size_t)o*64 + c4*4];
    #pragma unroll
    for (int t = 0; t < 10; ++t) {
      float4 y4 = *(const float4*)&ytile[(kg*10+t)*68 + c4*4];
      acc2[t] += y4.x*wv.x + y4.y*wv.y + y4.z*wv.z + y4.w*wv.w;
    }
  }
  #pragma unroll
  for (int t = 0; t < 10; ++t) y[(bn40 + kg*10+t)*64 + o] = acc2[t];
  double s = 0.0, s2 = 0.0;
  #pragma unroll
  for (int t = 0; t < 10; ++t) { double a = acc2[t]; s += a; s2 += a*a; }
  int slot = (blockIdx.y*NP + blockIdx.x) & (NSLOT-1);
  sred[kg][o] = s; __syncthreads();
  if (kg == 0) atomicAdd(&stslots[slot*128 + o], sred[0][o]+sred[1][o]+sred[2][o]+sred[3][o]);
  __syncthreads();
  sred[kg][o] = s2; __syncthreads();
  if (kg == 0) atomicAdd(&stslots[slot*128 + 64 + o], sred[0][o]+sred[1][o]+sred[2][o]+sred[3][o]);
}

// ---- maxk_bn: y(raw) -> bn+leaky -> max over k -> out(b,n,64) ----
__global__ __launch_bounds__(256) void maxk_bn_kernel(
    const float* __restrict__ y, const double* __restrict__ stp,
    const float* __restrict__ gv, const float* __restrict__ bv, float* __restrict__ out)
{
  int i = blockIdx.x*256 + threadIdx.x;
  if (i >= NB*NP*64) return;
  int o = i & 63; int bn = i >> 6;
  const double INV_M1 = 1.0/327680.0;
  double md = stp[o]*INV_M1;
  double vd = stp[64+o]*INV_M1 - md*md;
  float m = (float)md;
  float sc = gv[o]/sqrtf((float)vd + BEPS);
  float bo = bv[o];
  float mx = -INFINITY;
  size_t base = (size_t)bn*KNN;
  for (int k = 0; k < KNN; ++k) {
    float v = y[(base + k)*64 + o];
    mx = fmaxf(mx, leaky(sc*(v-m) + bo));
  }
  out[(size_t)bn*64 + o] = mx;
}

// ---------------- stats slot reduction (double) ----------------
__global__ __launch_bounds__(128) void redstats_kernel(const double* __restrict__ slots, double* __restrict__ st) {
  int c = threadIdx.x;
  double s = 0.0;
  for (int i = 0; i < NSLOT; ++i) s += slots[i*128 + c];
  st[c] = s;
}

// ---------------- allf (b,n,128) ----------------
__global__ __launch_bounds__(256) void allf_kernel(const float* __restrict__ rc, const float* __restrict__ drc,
                                                   float* __restrict__ out) {
  int i = blockIdx.x*256 + threadIdx.x;
  if (i >= NB*NP*128) return;
  int c = i & 127; int bn = i >> 7;
  out[i] = (c < 64) ? rc[(size_t)bn*64 + c] : drc[(size_t)bn*64 + (c-64)];
}

// ---------------- GEMM ----------------
#define GBM 64
#define GBN 64
#define GBK 16
__global__ __launch_bounds__(256) void gemm_kernel(const float* __restrict__ A, const float* __restrict__ W,
                                                   float* __restrict__ C, int M, int No, int Kd,
                                                   int wstride, int woff, const float* __restrict__ bias) {
  __shared__ __align__(16) float As[GBK][GBM+8];
  __shared__ __align__(16) float Ws[GBK][GBN+8];
  int bm = blockIdx.y * GBM, bn = blockIdx.x * GBN;
  int tid = threadIdx.x;
  int tx = tid % 16, ty = tid / 16;
  float acc[4][4] = {{0.f}};
  for (int k0 = 0; k0 < Kd; k0 += GBK) {
    for (int i = tid; i < GBM*GBK; i += 256) {
      int r = i / GBK, c = i % GBK;
      int gm = bm + r, gk = k0 + c;
      As[c][r] = (gk < Kd && gm < M) ? A[(size_t)gm*Kd + gk] : 0.f;
      int gn = bn + r;
      Ws[c][r] = (gk < Kd && gn < No) ? W[(size_t)gn*wstride + woff + gk] : 0.f;
    }
    __syncthreads();
    #pragma unroll
    for (int kk = 0; kk < GBK; ++kk) {
      float4 a4 = *(const float4*)&As[kk][ty*4];
      float4 w4 = *(const float4*)&Ws[kk][tx*4];
      float av[4] = {a4.x, a4.y, a4.z, a4.w};
      float wv[4] = {w4.x, w4.y, w4.z, w4.w};
      #pragma unroll
      for (int i2 = 0; i2 < 4; ++i2)
        #pragma unroll
        for (int j2 = 0; j2 < 4; ++j2)
          acc[i2][j2] += av[i2]*wv[j2];
    }
    __syncthreads();
  }
  for (int i2 = 0; i2 < 4; ++i2) {
    int gm = bm + ty*4 + i2;
    if (gm >= M) continue;
    for (int j2 = 0; j2 < 4; ++j2) {
      int gn = bn + tx*4 + j2;
      if (gn < No) {
        float v = acc[i2][j2];
        if (bias) v += bias[(gm >> 11)*No + gn];
        C[(size_t)gm*No + gn] = v;
      }
    }
  }
}

// ---------------- column stats (fp64) ----------------
__global__ __launch_bounds__(256) void colstats_kernel(const float* __restrict__ A, long M, int C,
                                                       int rowsPerBlock, double* __restrict__ st) {
  long r0 = (long)blockIdx.x * rowsPerBlock;
  long r1 = r0 + rowsPerBlock; if (r1 > M) r1 = M;
  int tid = threadIdx.x;
  if (C >= 256) {
    for (int c0 = 0; c0 < C; c0 += 256) {
      int c = c0 + tid;
      double s = 0.0, s2 = 0.0;
      for (long r = r0; r < r1; ++r) { double v = A[r*(long)C + c]; s += v; s2 += v*v; }
      atomicAdd(&st[c], s); atomicAdd(&st[C+c], s2);
    }
  } else {
    int c = tid % C; int grp = tid / C; int G = 256 / C;
    double s = 0.0, s2 = 0.0;
    for (long r = r0 + grp; r < r1; r += G) { double v = A[r*(long)C + c]; s += v; s2 += v*v; }
    __shared__ double sh[512];
    sh[tid] = s; sh[256+tid] = s2; __syncthreads();
    for (int g = G/2; g > 0; g >>= 1) {
      if (grp < g) { sh[tid] += sh[tid + g*C]; sh[256+tid] += sh[256+tid + g*C]; }
      __syncthreads();
    }
    if (grp == 0) { atomicAdd(&st[c], sh[tid]); atomicAdd(&st[C+c], sh[256+tid]); }
  }
}

// ---------------- BN apply + leaky (double stats) ----------------
__global__ __launch_bounds__(256) void bnapply_kernel(float* __restrict__ A, const double* __restrict__ st,
                                                      const float* __restrict__ g, const float* __restrict__ bb,
                                                      double invM, int cmask, size_t total) {
  size_t i = (size_t)blockIdx.x*256 + threadIdx.x;
  if (i >= total) return;
  int c = (int)(i & cmask);
  int C = cmask + 1;
  double md = st[c]*invM;
  double vd = st[C+c]*invM - md*md;
  float m = (float)md;
  float sc = g[c]/sqrtf((float)vd + BEPS);
  float y = sc*(A[i]-m) + bb[c];
  A[i] = leaky(y);
}

// ---------------- chunked column max (exact, order-independent) ----------------
__global__ __launch_bounds__(256) void colmax_part_kernel(const float* __restrict__ A, int C,
                                                          float* __restrict__ pmax) {
  int i = blockIdx.x*256 + threadIdx.x;
  if (i >= NB*CMCH*C) return;
  int c = i % C; int t = i / C; int ch = t % CMCH; int b = t / CMCH;
  int n0 = ch * (NP/CMCH);
  float mx = -INFINITY;
  for (int n = n0; n < n0 + NP/CMCH; ++n)
    mx = fmaxf(mx, A[((size_t)(b*NP+n))*C + c]);
  pmax[(size_t)(b*CMCH+ch)*C + c] = mx;
}
__global__ __launch_bounds__(256) void colmax_fin_kernel(const float* __restrict__ pmax, int C,
                                                         float* __restrict__ out) {
  int i = blockIdx.x*256 + threadIdx.x;
  if (i >= NB*C) return;
  int b = i / C, c = i % C;
  float mx = -INFINITY;
  for (int ch = 0; ch < CMCH; ++ch) mx = fmaxf(mx, pmax[(size_t)(b*CMCH+ch)*C + c]);
  out[i] = mx;
}

// ---------------- label vector branch ----------------
__global__ __launch_bounds__(256) void lv_kernel(const float* __restrict__ l, const float* __restrict__ W8,
                                                 const float* __restrict__ g8, const float* __restrict__ b8,
                                                 float* __restrict__ lv) {
  __shared__ float raw[4][64];
  int tid = threadIdx.x;
  {
    int b = tid / 64, o = tid % 64;
    float s = 0.f;
    for (int i = 0; i < 16; ++i) s += W8[o*16+i]*l[b*16+i];
    raw[b][o] = s;
  }
  __syncthreads();
  if (tid < 64) {
    int o = tid;
    float m = (raw[0][o]+raw[1][o]+raw[2][o]+raw[3][o])*0.25f;
    float v = 0.f;
    for (int b = 0; b < 4; ++b) { float d = raw[b][o]-m; v += d*d; }
    v *= 0.25f;
    float sc = g8[o]/sqrtf(v + BEPS);
    for (int b = 0; b < 4; ++b) {
      float y = sc*(raw[b][o]-m) + b8[o];
      lv[b*64+o] = leaky(y);
    }
  }
}

// ---------------- bias9 ----------------
__global__ __launch_bounds__(256) void bias9_kernel(const float* __restrict__ hmax, const float* __restrict__ lv,
                                                    const float* __restrict__ W9, float* __restrict__ bias9) {
  int i = blockIdx.x*256 + threadIdx.x;
  if (i >= 4*512) return;
  int b = i >> 9, o = i & 511;
  const float* wr = &W9[(size_t)o*1216];
  float s = 0.f;
  for (int c = 0; c < 1024; ++c) s += hmax[b*1024+c]*wr[c];
  for (int c = 0; c < 64; ++c) s += lv[b*64+c]*wr[1024+c];
  bias9[i] = s;
}

// ---------------- final transpose ----------------
__global__ __launch_bounds__(256) void out_kernel(const float* __restrict__ h5, float* __restrict__ out) {
  int i = blockIdx.x*256 + threadIdx.x;
  if (i >= NB*50*NP) return;
  int n = i % NP; int t = i / NP; int o = t % 50; int b = t / 50;
  out[i] = h5[((size_t)(b*NP+n))*50 + o];
}

// ================= host side =================
extern "C" void kernel_launch(void* const* d_in, const int* in_sizes, int n_in,
                              void* d_out, int out_size, void* d_ws, size_t ws_size,
                              hipStream_t stream) {
  const float* x   = (const float*)d_in[0];
  const float* l   = (const float*)d_in[1];
  const float* W3  = (const float*)d_in[2];
  const float* W4  = (const float*)d_in[3];
  const float* W5  = (const float*)d_in[4];
  const float* W6  = (const float*)d_in[5];
  const float* W7  = (const float*)d_in[6];
  const float* W8  = (const float*)d_in[7];
  const float* W9  = (const float*)d_in[8];
  const float* W10 = (const float*)d_in[9];
  const float* W11 = (const float*)d_in[10];
  const float* W12 = (const float*)d_in[11];
  const float* g3 = (const float*)d_in[12], *b3 = (const float*)d_in[13];
  const float* g4 = (const float*)d_in[14], *b4 = (const float*)d_in[15];
  const float* g5 = (const float*)d_in[16], *b5 = (const float*)d_in[17];
  const float* g6 = (const float*)d_in[18], *b6 = (const float*)d_in[19];
  const float* g7 = (const float*)d_in[20], *b7 = (const float*)d_in[21];
  const float* g8 = (const float*)d_in[22], *b8 = (const float*)d_in[23];
  const float* g9 = (const float*)d_in[24], *b9 = (const float*)d_in[25];
  const float* g10 = (const float*)d_in[26], *b10 = (const float*)d_in[27];
  const float* g11 = (const float*)d_in[28], *b11 = (const float*)d_in[29];
  (void)in_sizes; (void)n_in;

  constexpr size_t OFF_IDX1 = 0;
  constexpr size_t OFF_IDX2 = OFF_IDX1 + (size_t)NB*NP*KNN*4;
  constexpr size_t OFF_RC   = OFF_IDX2 + (size_t)NB*NP*KNN*4;
  constexpr size_t OFF_DRC  = OFF_RC   + (size_t)NB*NP*64*4;
  constexpr size_t OFF_XX   = OFF_DRC  + (size_t)NB*NP*64*4;
  constexpr size_t OFF_SLOT = OFF_XX   + (size_t)NB*NP*4;
  constexpr size_t OFF_ST3  = OFF_SLOT + (size_t)NSLOT*128*8;
  constexpr size_t OFF_ST4  = OFF_ST3 + 128*8;
  constexpr size_t OFF_ST5  = OFF_ST4 + 128*8;
  constexpr size_t OFF_ST6  = OFF_ST5 + 128*8;
  constexpr size_t OFF_STH  = OFF_ST6 + 128*8;
  constexpr size_t OFF_HMAX = OFF_STH + 2*1024*8;
  constexpr size_t OFF_LV   = OFF_HMAX + 4*1024*4;
  constexpr size_t OFF_B9   = OFF_LV + 4096;
  constexpr size_t OFF_PMAX = OFF_B9 + 4*512*4;
  constexpr size_t OFF_ALLF = OFF_PMAX + (size_t)NB*CMCH*1024*4;
  constexpr size_t OFF_H1   = OFF_ALLF + (size_t)NB*NP*128*4;
  constexpr size_t SZ_H1    = (size_t)NB*NP*1024*4;
  constexpr size_t OFF_END  = OFF_H1 + SZ_H1;
  constexpr size_t OFF_H2 = OFF_H1;
  constexpr size_t OFF_H3 = OFF_H2 + (size_t)NB*NP*512*4;
  constexpr size_t OFF_H4 = OFF_H3 + (size_t)NB*NP*256*4;
  constexpr size_t OFF_H5 = OFF_H4 + (size_t)NB*NP*128*4;
  static_assert(OFF_H5 + (size_t)NB*NP*50*4 <= OFF_END, "h alias overflow");
  // fast-path y buffer
  constexpr size_t OFF_Y   = OFF_END;
  constexpr size_t SZ_Y    = (size_t)NB*NP*KNN*64*4;   // 83,886,080
  constexpr size_t OFF_FAST_END = OFF_Y + SZ_Y;

  if (ws_size < OFF_END) {
    canary_kernel<<<(out_size + 255)/256, 256, 0, stream>>>((float*)d_out, out_size, (float)(ws_size >> 20));
    return;
  }
  const bool FAST = (ws_size >= OFF_FAST_END);

  char* ws = (char*)d_ws;
  int*    idx1  = (int*)(ws + OFF_IDX1);
  int*    idx2  = (int*)(ws + OFF_IDX2);
  float*  rc    = (float*)(ws + OFF_RC);
  float*  drc   = (float*)(ws + OFF_DRC);
  float*  xx2   = (float*)(ws + OFF_XX);
  double* slots = (double*)(ws + OFF_SLOT);
  double* st3s  = (double*)(ws + OFF_ST3);
  double* st4s  = (double*)(ws + OFF_ST4);
  double* st5s  = (double*)(ws + OFF_ST5);
  double* st6s  = (double*)(ws + OFF_ST6);
  double* sth   = (double*)(ws + OFF_STH);
  float*  hmaxb = (float*)(ws + OFF_HMAX);
  float*  lvb   = (float*)(ws + OFF_LV);
  float*  bias9 = (float*)(ws + OFF_B9);
  float*  pmaxb = (float*)(ws + OFF_PMAX);
  float*  allf  = (float*)(ws + OFF_ALLF);
  float*  h1    = (float*)(ws + OFF_H1);
  float*  h2    = (float*)(ws + OFF_H2);
  float*  h3    = (float*)(ws + OFF_H3);
  float*  h4    = (float*)(ws + OFF_H4);
  float*  h5    = (float*)(ws + OFF_H5);
  float*  ybuf  = (float*)(ws + OFF_Y);

  dim3 gridNP(NP, NB);
  dim3 gridKNN4(NP/4, NB);
  const size_t slotBytes = (size_t)NSLOT*128*8;
  const double INV_M2 = 1.0/8192.0;

  // ---- stage 1 ----
  knn3_kernel<<<gridKNN4, 256, 0, stream>>>(x, idx1);
  hipMemsetAsync(slots, 0, slotBytes, stream);
  s1a_kernel<<<gridNP, 256, 0, stream>>>(x, idx1, W3, slots, FAST ? ybuf : h1);
  redstats_kernel<<<1, 128, 0, stream>>>(slots, st3s);
  hipMemsetAsync(slots, 0, slotBytes, stream);
  mid_kernel<<<gridNP, 256, 0, stream>>>(FAST ? ybuf : h1, W4, st3s, g3, b3, slots);
  redstats_kernel<<<1, 128, 0, stream>>>(slots, st4s);
  maxk_bn_kernel<<<(NB*NP*64 + 255)/256, 256, 0, stream>>>(FAST ? ybuf : h1, st4s, g4, b4, rc);

  // ---- stage 2 ----
  xx64_kernel<<<(NB*NP + 255)/256, 256, 0, stream>>>(rc, xx2);
  knn64_kernel<<<gridKNN4, 256, 0, stream>>>(rc, xx2, idx2);
  hipMemsetAsync(slots, 0, slotBytes, stream);
  s2a_kernel<<<gridNP, 256, 0, stream>>>(rc, idx2, W5, slots, FAST ? ybuf : h1);
  redstats_kernel<<<1, 128, 0, stream>>>(slots, st5s);
  hipMemsetAsync(slots, 0, slotBytes, stream);
  mid_kernel<<<gridNP, 256, 0, stream>>>(FAST ? ybuf : h1, W6, st5s, g5, b5, slots);
  redstats_kernel<<<1, 128, 0, stream>>>(slots, st6s);
  maxk_bn_kernel<<<(NB*NP*64 + 255)/256, 256, 0, stream>>>(FAST ? ybuf : h1, st6s, g6, b6, drc);

  // ---- stage 3: global head ----
  allf_kernel<<<(NB*NP*128 + 255)/256, 256, 0, stream>>>(rc, drc, allf);
  gemm_kernel<<<dim3(1024/GBN, 8192/GBM), 256, 0, stream>>>(allf, W7, h1, 8192, 1024, 128, 128, 0, nullptr);
  hipMemsetAsync(sth, 0, 2*1024*8, stream);
  colstats_kernel<<<128, 256, 0, stream>>>(h1, 8192, 1024, 64, sth);
  bnapply_kernel<<<(unsigned)(((size_t)8192*1024 + 255)/256), 256, 0, stream>>>(h1, sth, g7, b7, INV_M2, 1023, (size_t)8192*1024);
  colmax_part_kernel<<<(NB*CMCH*1024 + 255)/256, 256, 0, stream>>>(h1, 1024, pmaxb);
  colmax_fin_kernel<<<(NB*1024 + 255)/256, 256, 0, stream>>>(pmaxb, 1024, hmaxb);
  lv_kernel<<<1, 256, 0, stream>>>(l, W8, g8, b8, lvb);
  bias9_kernel<<<8, 256, 0, stream>>>(hmaxb, lvb, W9, bias9);

  gemm_kernel<<<dim3(512/GBN, 8192/GBM), 256, 0, stream>>>(allf, W9, h2, 8192, 512, 128, 1216, 1088, bias9);
  hipMemsetAsync(sth, 0, 2*512*8, stream);
  colstats_kernel<<<128, 256, 0, stream>>>(h2, 8192, 512, 64, sth);
  bnapply_kernel<<<(unsigned)(((size_t)8192*512 + 255)/256), 256, 0, stream>>>(h2, sth, g9, b9, INV_M2, 511, (size_t)8192*512);

  gemm_kernel<<<dim3(256/GBN, 8192/GBM), 256, 0, stream>>>(h2, W10, h3, 8192, 256, 512, 512, 0, nullptr);
  hipMemsetAsync(sth, 0, 2*256*8, stream);
  colstats_kernel<<<128, 256, 0, stream>>>(h3, 8192, 256, 64, sth);
  bnapply_kernel<<<(unsigned)(((size_t)8192*256 + 255)/256), 256, 0, stream>>>(h3, sth, g10, b10, INV_M2, 255, (size_t)8192*256);

  gemm_kernel<<<dim3(128/GBN, 8192/GBM), 256, 0, stream>>>(h3, W11, h4, 8192, 128, 256, 256, 0, nullptr);
  hipMemsetAsync(sth, 0, 2*128*8, stream);
  colstats_kernel<<<128, 256, 0, stream>>>(h4, 8192, 128, 64, sth);
  bnapply_kernel<<<(unsigned)(((size_t)8192*128 + 255)/256), 256, 0, stream>>>(h4, sth, g11, b11, INV_M2, 127, (size_t)8192*128);

  gemm_kernel<<<dim3(1, 8192/GBM), 256, 0, stream>>>(h4, W12, h5, 8192, 50, 128, 128, 0, nullptr);
  out_kernel<<<(NB*50*NP + 255)/256, 256, 0, stream>>>(h5, (float*)d_out);
}

// Round 25
// 1478.966 us; speedup vs baseline: 1.2277x; 1.2277x over previous
//
#include <hip/hip_runtime.h>
#include <math.h>

#define NB 4
#define NP 2048
#define KNN 40
#define BEPS 1e-5f
#define NSLOT 64
#define CMCH 16

typedef unsigned long long u64;

static __device__ __forceinline__ float leaky(float x) { return x >= 0.f ? x : 0.2f * x; }

// key: fp32 value (order-preserving bijection to u32) + lower-index tie-break
static __device__ __forceinline__ u64 keyOf(float v, int m) {
  unsigned u = __float_as_uint(v);
  u ^= (u >> 31) ? 0xFFFFFFFFu : 0x80000000u;
  return ((u64)u << 32) | (unsigned)(NP - 1 - m);
}
static __device__ __forceinline__ u64 umax64(u64 a, u64 b) { return a > b ? a : b; }

// ---------------- parallel-half top-40: 2 queries/block, each half selects one query ----------------
static __device__ __forceinline__ void select40_dual(float (*pd)[NP], int* __restrict__ out0,
                                                     int* __restrict__ out1, int tid,
                                                     u64* red, u64* red2, int* sh_w) {
  int h = tid >> 7, t = tid & 127;
  int* outp = h ? out1 : out0;
  u64 myBest = 0;
  #pragma unroll
  for (int j = 0; j < 16; ++j) myBest = umax64(myBest, keyOf(pd[h][t + j*128], t + j*128));
  for (int kk = 0; kk < KNN; ++kk) {
    red[tid] = myBest;
    __syncthreads();
    if (t < 16) {
      u64 v = red[h*128 + t];
      #pragma unroll
      for (int j = 1; j < 8; ++j) v = umax64(v, red[h*128 + t + j*16]);
      red2[h*16 + t] = v;
    }
    __syncthreads();
    if (t == 0) {
      u64 v = red2[h*16];
      #pragma unroll
      for (int j = 1; j < 16; ++j) v = umax64(v, red2[h*16 + j]);
      int w = NP - 1 - (int)(v & 0xFFFFFFFFu);
      outp[kk] = w;
      pd[h][w] = -INFINITY;
      sh_w[h] = w;
    }
    __syncthreads();
    if ((sh_w[h] & 127) == t) {
      u64 nb = 0;
      #pragma unroll
      for (int j = 0; j < 16; ++j) nb = umax64(nb, keyOf(pd[h][t + j*128], t + j*128));
      myBest = nb;
    }
  }
}

// ---------------- canary ----------------
__global__ __launch_bounds__(256) void canary_kernel(float* __restrict__ out, int n, float val) {
  int i = blockIdx.x*256 + threadIdx.x;
  if (i < n) out[i] = val;
}

// ---------------- knn for C=3 — 2 queries/block, shared x rows, parallel-half select ----------------
__global__ __launch_bounds__(256) void knn3_kernel(const float* __restrict__ x, int* __restrict__ idx) {
  int b = blockIdx.y, n0 = blockIdx.x*2, tid = threadIdx.x;
  __shared__ float pd[2][NP];
  __shared__ float xq[2][3];
  __shared__ float xxq[2];
  __shared__ u64 red[256];
  __shared__ u64 red2[32];
  __shared__ int sh_w[2];
  if (tid < 2) {
    int n = n0 + tid;
    float a0 = x[(b*3+0)*NP+n], a1 = x[(b*3+1)*NP+n], a2 = x[(b*3+2)*NP+n];
    xq[tid][0] = a0; xq[tid][1] = a1; xq[tid][2] = a2;
    xxq[tid] = __fadd_rn(__fadd_rn(__fmul_rn(a0,a0), __fmul_rn(a1,a1)), __fmul_rn(a2,a2));
  }
  __syncthreads();
  for (int m = tid; m < NP; m += 256) {
    float m0 = x[(b*3+0)*NP+m], m1 = x[(b*3+1)*NP+m], m2 = x[(b*3+2)*NP+m];
    float xxm = __fadd_rn(__fadd_rn(__fmul_rn(m0,m0), __fmul_rn(m1,m1)), __fmul_rn(m2,m2));
    #pragma unroll
    for (int q = 0; q < 2; ++q) {
      float dot = __fmaf_rn(xq[q][2], m2, __fmaf_rn(xq[q][1], m1, __fmul_rn(xq[q][0], m0)));
      float inner = __fmul_rn(-2.f, dot);
      pd[q][m] = __fsub_rn(__fsub_rn(-xxm, inner), xxq[q]);
    }
  }
  __syncthreads();
  select40_dual(pd, &idx[((size_t)b*NP + n0)*KNN], &idx[((size_t)b*NP + n0 + 1)*KNN], tid, red, red2, sh_w);
}

// ---------------- xx for 64-channel rc — sequential no-FMA (XLA reduce) ----------------
__global__ __launch_bounds__(256) void xx64_kernel(const float* __restrict__ rc, float* __restrict__ xx) {
  int i = blockIdx.x*256 + threadIdx.x;
  if (i >= NB*NP) return;
  const float* p = &rc[(size_t)i*64];
  float s = __fmul_rn(p[0], p[0]);
  #pragma unroll
  for (int c = 1; c < 64; ++c) s = __fadd_rn(s, __fmul_rn(p[c], p[c]));
  xx[i] = s;
}

// ---------------- knn for C=64 — 2 queries/block shared-row dot + parallel-half select ----------------
__global__ __launch_bounds__(256) void knn64_kernel(const float* __restrict__ rc, const float* __restrict__ xx,
                                                    int* __restrict__ idx) {
  int b = blockIdx.y, n0 = blockIdx.x*2, tid = threadIdx.x;
  __shared__ float pd[2][NP];
  __shared__ float xn[2][64];
  __shared__ u64 red[256];
  __shared__ u64 red2[32];
  __shared__ int sh_w[2];
  if (tid < 128) xn[tid >> 6][tid & 63] = rc[((size_t)b*NP + n0 + (tid >> 6))*64 + (tid & 63)];
  __syncthreads();
  float xxn0 = xx[b*NP + n0], xxn1 = xx[b*NP + n0 + 1];
  for (int m = tid; m < NP; m += 256) {
    const float* xm = &rc[((size_t)b*NP + m)*64];
    float v0 = xm[0];
    float d0 = __fmul_rn(xn[0][0], v0);
    float d1 = __fmul_rn(xn[1][0], v0);
    #pragma unroll
    for (int c = 1; c < 64; ++c) {
      float v = xm[c];
      d0 = __fmaf_rn(xn[0][c], v, d0);
      d1 = __fmaf_rn(xn[1][c], v, d1);
    }
    float xxm = xx[b*NP + m];
    pd[0][m] = __fsub_rn(__fsub_rn(-xxm, __fmul_rn(-2.f, d0)), xxn0);
    pd[1][m] = __fsub_rn(__fsub_rn(-xxm, __fmul_rn(-2.f, d1)), xxn1);
  }
  __syncthreads();
  select40_dual(pd, &idx[((size_t)b*NP + n0)*KNN], &idx[((size_t)b*NP + n0 + 1)*KNN], tid, red, red2, sh_w);
}

// ================= FAST PATH: single-compute passes via global y buffer =================

// ---- s1a: gc1(46) + W3 -> y raw + stats3 (UNCHANGED — feeds rc, discrete path) ----
__global__ __launch_bounds__(256) void s1a_kernel(
    const float* __restrict__ x, const int* __restrict__ idx1, const float* __restrict__ W3,
    double* __restrict__ stslots, float* __restrict__ y)
{
  int b = blockIdx.y, n = blockIdx.x, tid = threadIdx.x;
  __shared__ int sidx[4][KNN];
  __shared__ float rs[KNN][4];
  __shared__ float ns[KNN][4];
  __shared__ float scale[3];
  __shared__ __align__(16) float feat[KNN*48];
  __shared__ float w3s[64*48];
  __shared__ double sred[4][64];

  for (int i = tid; i < 4*KNN; i += 256) sidx[i/KNN][i%KNN] = idx1[((i/KNN)*NP + n)*KNN + (i%KNN)];
  for (int i = tid; i < 64*48; i += 256) { int o = i/48, ci = i%48; w3s[i] = (ci < 46) ? W3[o*46+ci] : 0.f; }
  __syncthreads();
  for (int i = tid; i < KNN*3; i += 256) {
    int k = i/3, c = i%3;
    float ctr = x[(b*3+c)*NP + n];
    float r = x[(b*3+c)*NP + sidx[b][k]] - ctr;
    float s = 0.f;
    for (int b2 = 0; b2 < 4; ++b2) s += x[(b2*3+c)*NP + sidx[b2][k]] - x[(b2*3+c)*NP + n];
    rs[k][c] = r; ns[k][c] = r - 0.25f*s;
  }
  __syncthreads();
  if (tid < 3) {
    float s = 0.f; for (int k = 0; k < KNN; ++k) s += rs[k][tid];
    float m = s/(float)KNN; float v = 0.f;
    for (int k = 0; k < KNN; ++k) { float d = rs[k][tid]-m; v += d*d; }
    scale[tid] = 1.f - v/(float)(KNN-1);
  }
  __syncthreads();
  for (int i = tid; i < KNN*48; i += 256) {
    int k = i/48, ci = i%48; float v;
    if (ci < 3) v = x[(b*3+ci)*NP+n];
    else if (ci < 6) v = rs[k][ci-3]*scale[ci-3];
    else if (ci < 46) { int j = ci-6; v = rs[k][0]*ns[j][0] + rs[k][1]*ns[j][1] + rs[k][2]*ns[j][2]; }
    else v = 0.f;
    feat[i] = v;
  }
  __syncthreads();

  int o = tid & 63, kg = tid >> 6;
  float acc[10];
  #pragma unroll
  for (int t = 0; t < 10; ++t) acc[t] = 0.f;
  for (int ci4 = 0; ci4 < 12; ++ci4) {
    float w0 = w3s[o*48+ci4*4+0], w1 = w3s[o*48+ci4*4+1], w2 = w3s[o*48+ci4*4+2], w3c = w3s[o*48+ci4*4+3];
    #pragma unroll
    for (int t = 0; t < 10; ++t) {
      float4 f4 = *(const float4*)&feat[(kg*10+t)*48 + ci4*4];
      acc[t] += f4.x*w0 + f4.y*w1 + f4.z*w2 + f4.w*w3c;
    }
  }
  size_t bn40 = (size_t)(b*NP+n)*KNN;
  #pragma unroll
  for (int t = 0; t < 10; ++t) y[(bn40 + kg*10+t)*64 + o] = acc[t];
  double s = 0.0, s2 = 0.0;
  #pragma unroll
  for (int t = 0; t < 10; ++t) { double a = acc[t]; s += a; s2 += a*a; }
  int slot = (blockIdx.y*NP + blockIdx.x) & (NSLOT-1);
  sred[kg][o] = s; __syncthreads();
  if (kg == 0) atomicAdd(&stslots[slot*128 + o], sred[0][o]+sred[1][o]+sred[2][o]+sred[3][o]);
  __syncthreads();
  sred[kg][o] = s2; __syncthreads();
  if (kg == 0) atomicAdd(&stslots[slot*128 + 64 + o], sred[0][o]+sred[1][o]+sred[2][o]+sred[3][o]);
}

// ---- s2a: gc2(168) + W5 -> y raw + stats5, REASSOCIATED: u[o][c] folds scale+cov terms ----
__global__ __launch_bounds__(256) void s2a_kernel(
    const float* __restrict__ rc, const int* __restrict__ idx2, const float* __restrict__ W5,
    double* __restrict__ stslots, float* __restrict__ y)
{
  int b = blockIdx.y, n = blockIdx.x, tid = threadIdx.x;
  __shared__ int sidx[4][KNN];
  __shared__ float rsT[64*41];
  __shared__ float nsT[64*41];
  __shared__ float scale[64];
  __shared__ float u[64*65];
  __shared__ float acc0s[64];
  __shared__ double sred[4][64];

  for (int i = tid; i < 4*KNN; i += 256) sidx[i/KNN][i%KNN] = idx2[((i/KNN)*NP + n)*KNN + (i%KNN)];
  __syncthreads();
  for (int i = tid; i < KNN*64; i += 256) {
    int k = i >> 6, c = i & 63;
    float ctr = rc[((size_t)(b*NP+n))*64 + c];
    float r = rc[((size_t)(b*NP) + sidx[b][k])*64 + c] - ctr;
    float s = 0.f;
    for (int b2 = 0; b2 < 4; ++b2)
      s += rc[((size_t)(b2*NP) + sidx[b2][k])*64 + c] - rc[((size_t)(b2*NP+n))*64 + c];
    rsT[c*41+k] = r; nsT[c*41+k] = r - 0.25f*s;
  }
  __syncthreads();
  if (tid < 64) {
    int c = tid;
    float s = 0.f; for (int k = 0; k < KNN; ++k) s += rsT[c*41+k];
    float m = s/(float)KNN; float v = 0.f;
    for (int k = 0; k < KNN; ++k) { float d = rsT[c*41+k]-m; v += d*d; }
    scale[c] = 1.f - v/(float)(KNN-1);
  }
  __syncthreads();
  for (int i = tid; i < 64*64; i += 256) {
    int o = i >> 6, c = i & 63;
    const float* wr = &W5[(size_t)o*168];
    float a = __fmul_rn(wr[64+c], scale[c]);
    #pragma unroll 8
    for (int j = 0; j < KNN; ++j) a = __fmaf_rn(wr[128+j], nsT[c*41+j], a);
    u[o*65+c] = a;
  }
  if (tid < 64) {
    int o = tid;
    const float* wr = &W5[(size_t)o*168];
    const float* xc = &rc[((size_t)(b*NP+n))*64];
    float a = 0.f;
    for (int c = 0; c < 64; ++c) a = __fmaf_rn(wr[c], xc[c], a);
    acc0s[o] = a;
  }
  __syncthreads();

  int o = tid & 63, kg = tid >> 6;
  float acc[10];
  #pragma unroll
  for (int t = 0; t < 10; ++t) acc[t] = acc0s[o];
  for (int c = 0; c < 64; ++c) {
    float uoc = u[o*65+c];
    const float* rsc = &rsT[c*41 + kg*10];
    #pragma unroll
    for (int t = 0; t < 10; ++t) acc[t] = __fmaf_rn(rsc[t], uoc, acc[t]);
  }
  size_t bn40 = (size_t)(b*NP+n)*KNN;
  #pragma unroll
  for (int t = 0; t < 10; ++t) y[(bn40 + kg*10+t)*64 + o] = acc[t];
  double s = 0.0, s2 = 0.0;
  #pragma unroll
  for (int t = 0; t < 10; ++t) { double a = acc[t]; s += a; s2 += a*a; }
  int slot = (blockIdx.y*NP + blockIdx.x) & (NSLOT-1);
  sred[kg][o] = s; __syncthreads();
  if (kg == 0) atomicAdd(&stslots[slot*128 + o], sred[0][o]+sred[1][o]+sred[2][o]+sred[3][o]);
  __syncthreads();
  sred[kg][o] = s2; __syncthreads();
  if (kg == 0) atomicAdd(&stslots[slot*128 + 64 + o], sred[0][o]+sred[1][o]+sred[2][o]+sred[3][o]);
}

// ---- mid: y(raw) -> bn(st_prev)+leaky -> 64x64 GEMM W -> y (in-place) + stats ----
__global__ __launch_bounds__(256) void mid_kernel(
    float* __restrict__ y, const float* __restrict__ W,
    const double* __restrict__ stp, const float* __restrict__ gv, const float* __restrict__ bv,
    double* __restrict__ stslots)
{
  int b = blockIdx.y, n = blockIdx.x, tid = threadIdx.x;
  __shared__ float m_s[64], sc_s[64], bo_s[64];
  __shared__ __align__(16) float ytile[KNN*68];
  __shared__ double sred[4][64];
  const double INV_M1 = 1.0/327680.0;

  if (tid < 64) {
    double md = stp[tid]*INV_M1;
    double vd = stp[64+tid]*INV_M1 - md*md;
    m_s[tid] = (float)md;
    sc_s[tid] = gv[tid]/sqrtf((float)vd + BEPS);
    bo_s[tid] = bv[tid];
  }
  __syncthreads();
  size_t bn40 = (size_t)(b*NP+n)*KNN;
  for (int i = tid; i < KNN*64; i += 256) {
    int k = i >> 6, c = i & 63;
    float v = y[(bn40 + k)*64 + c];
    ytile[k*68+c] = leaky(sc_s[c]*(v - m_s[c]) + bo_s[c]);
  }
  __syncthreads();
  int o = tid & 63, kg = tid >> 6;
  float acc2[10];
  #pragma unroll
  for (int t = 0; t < 10; ++t) acc2[t] = 0.f;
  for (int c4 = 0; c4 < 16; ++c4) {
    float4 wv = *(const float4*)&W[(size_t)o*64 + c4*4];
    #pragma unroll
    for (int t = 0; t < 10; ++t) {
      float4 y4 = *(const float4*)&ytile[(kg*10+t)*68 + c4*4];
      acc2[t] += y4.x*wv.x + y4.y*wv.y + y4.z*wv.z + y4.w*wv.w;
    }
  }
  #pragma unroll
  for (int t = 0; t < 10; ++t) y[(bn40 + kg*10+t)*64 + o] = acc2[t];
  double s = 0.0, s2 = 0.0;
  #pragma unroll
  for (int t = 0; t < 10; ++t) { double a = acc2[t]; s += a; s2 += a*a; }
  int slot = (blockIdx.y*NP + blockIdx.x) & (NSLOT-1);
  sred[kg][o] = s; __syncthreads();
  if (kg == 0) atomicAdd(&stslots[slot*128 + o], sred[0][o]+sred[1][o]+sred[2][o]+sred[3][o]);
  __syncthreads();
  sred[kg][o] = s2; __syncthreads();
  if (kg == 0) atomicAdd(&stslots[slot*128 + 64 + o], sred[0][o]+sred[1][o]+sred[2][o]+sred[3][o]);
}

// ---- maxk_bn: y(raw) -> bn+leaky -> max over k -> out(b,n,64) ----
__global__ __launch_bounds__(256) void maxk_bn_kernel(
    const float* __restrict__ y, const double* __restrict__ stp,
    const float* __restrict__ gv, const float* __restrict__ bv, float* __restrict__ out)
{
  int i = blockIdx.x*256 + threadIdx.x;
  if (i >= NB*NP*64) return;
  int o = i & 63; int bn = i >> 6;
  const double INV_M1 = 1.0/327680.0;
  double md = stp[o]*INV_M1;
  double vd = stp[64+o]*INV_M1 - md*md;
  float m = (float)md;
  float sc = gv[o]/sqrtf((float)vd + BEPS);
  float bo = bv[o];
  float mx = -INFINITY;
  size_t base = (size_t)bn*KNN;
  for (int k = 0; k < KNN; ++k) {
    float v = y[(base + k)*64 + o];
    mx = fmaxf(mx, leaky(sc*(v-m) + bo));
  }
  out[(size_t)bn*64 + o] = mx;
}

// ---------------- stats slot reduction (double) ----------------
__global__ __launch_bounds__(128) void redstats_kernel(const double* __restrict__ slots, double* __restrict__ st) {
  int c = threadIdx.x;
  double s = 0.0;
  for (int i = 0; i < NSLOT; ++i) s += slots[i*128 + c];
  st[c] = s;
}

// ---------------- allf (b,n,128) ----------------
__global__ __launch_bounds__(256) void allf_kernel(const float* __restrict__ rc, const float* __restrict__ drc,
                                                   float* __restrict__ out) {
  int i = blockIdx.x*256 + threadIdx.x;
  if (i >= NB*NP*128) return;
  int c = i & 127; int bn = i >> 7;
  out[i] = (c < 64) ? rc[(size_t)bn*64 + c] : drc[(size_t)bn*64 + (c-64)];
}

// ---------------- GEMM ----------------
#define GBM 64
#define GBN 64
#define GBK 16
__global__ __launch_bounds__(256) void gemm_kernel(const float* __restrict__ A, const float* __restrict__ W,
                                                   float* __restrict__ C, int M, int No, int Kd,
                                                   int wstride, int woff, const float* __restrict__ bias) {
  __shared__ __align__(16) float As[GBK][GBM+8];
  __shared__ __align__(16) float Ws[GBK][GBN+8];
  int bm = blockIdx.y * GBM, bn = blockIdx.x * GBN;
  int tid = threadIdx.x;
  int tx = tid % 16, ty = tid / 16;
  float acc[4][4] = {{0.f}};
  for (int k0 = 0; k0 < Kd; k0 += GBK) {
    for (int i = tid; i < GBM*GBK; i += 256) {
      int r = i / GBK, c = i % GBK;
      int gm = bm + r, gk = k0 + c;
      As[c][r] = (gk < Kd && gm < M) ? A[(size_t)gm*Kd + gk] : 0.f;
      int gn = bn + r;
      Ws[c][r] = (gk < Kd && gn < No) ? W[(size_t)gn*wstride + woff + gk] : 0.f;
    }
    __syncthreads();
    #pragma unroll
    for (int kk = 0; kk < GBK; ++kk) {
      float4 a4 = *(const float4*)&As[kk][ty*4];
      float4 w4 = *(const float4*)&Ws[kk][tx*4];
      float av[4] = {a4.x, a4.y, a4.z, a4.w};
      float wv[4] = {w4.x, w4.y, w4.z, w4.w};
      #pragma unroll
      for (int i2 = 0; i2 < 4; ++i2)
        #pragma unroll
        for (int j2 = 0; j2 < 4; ++j2)
          acc[i2][j2] += av[i2]*wv[j2];
    }
    __syncthreads();
  }
  for (int i2 = 0; i2 < 4; ++i2) {
    int gm = bm + ty*4 + i2;
    if (gm >= M) continue;
    for (int j2 = 0; j2 < 4; ++j2) {
      int gn = bn + tx*4 + j2;
      if (gn < No) {
        float v = acc[i2][j2];
        if (bias) v += bias[(gm >> 11)*No + gn];
        C[(size_t)gm*No + gn] = v;
      }
    }
  }
}

// ---------------- column stats (fp64) ----------------
__global__ __launch_bounds__(256) void colstats_kernel(const float* __restrict__ A, long M, int C,
                                                       int rowsPerBlock, double* __restrict__ st) {
  long r0 = (long)blockIdx.x * rowsPerBlock;
  long r1 = r0 + rowsPerBlock; if (r1 > M) r1 = M;
  int tid = threadIdx.x;
  if (C >= 256) {
    for (int c0 = 0; c0 < C; c0 += 256) {
      int c = c0 + tid;
      double s = 0.0, s2 = 0.0;
      for (long r = r0; r < r1; ++r) { double v = A[r*(long)C + c]; s += v; s2 += v*v; }
      atomicAdd(&st[c], s); atomicAdd(&st[C+c], s2);
    }
  } else {
    int c = tid % C; int grp = tid / C; int G = 256 / C;
    double s = 0.0, s2 = 0.0;
    for (long r = r0 + grp; r < r1; r += G) { double v = A[r*(long)C + c]; s += v; s2 += v*v; }
    __shared__ double sh[512];
    sh[tid] = s; sh[256+tid] = s2; __syncthreads();
    for (int g = G/2; g > 0; g >>= 1) {
      if (grp < g) { sh[tid] += sh[tid + g*C]; sh[256+tid] += sh[256+tid + g*C]; }
      __syncthreads();
    }
    if (grp == 0) { atomicAdd(&st[c], sh[tid]); atomicAdd(&st[C+c], sh[256+tid]); }
  }
}

// ---------------- BN apply + leaky (double stats) ----------------
__global__ __launch_bounds__(256) void bnapply_kernel(float* __restrict__ A, const double* __restrict__ st,
                                                      const float* __restrict__ g, const float* __restrict__ bb,
                                                      double invM, int cmask, size_t total) {
  size_t i = (size_t)blockIdx.x*256 + threadIdx.x;
  if (i >= total) return;
  int c = (int)(i & cmask);
  int C = cmask + 1;
  double md = st[c]*invM;
  double vd = st[C+c]*invM - md*md;
  float m = (float)md;
  float sc = g[c]/sqrtf((float)vd + BEPS);
  float y = sc*(A[i]-m) + bb[c];
  A[i] = leaky(y);
}

// ---------------- chunked column max (exact, order-independent) ----------------
__global__ __launch_bounds__(256) void colmax_part_kernel(const float* __restrict__ A, int C,
                                                          float* __restrict__ pmax) {
  int i = blockIdx.x*256 + threadIdx.x;
  if (i >= NB*CMCH*C) return;
  int c = i % C; int t = i / C; int ch = t % CMCH; int b = t / CMCH;
  int n0 = ch * (NP/CMCH);
  float mx = -INFINITY;
  for (int n = n0; n < n0 + NP/CMCH; ++n)
    mx = fmaxf(mx, A[((size_t)(b*NP+n))*C + c]);
  pmax[(size_t)(b*CMCH+ch)*C + c] = mx;
}
__global__ __launch_bounds__(256) void colmax_fin_kernel(const float* __restrict__ pmax, int C,
                                                         float* __restrict__ out) {
  int i = blockIdx.x*256 + threadIdx.x;
  if (i >= NB*C) return;
  int b = i / C, c = i % C;
  float mx = -INFINITY;
  for (int ch = 0; ch < CMCH; ++ch) mx = fmaxf(mx, pmax[(size_t)(b*CMCH+ch)*C + c]);
  out[i] = mx;
}

// ---------------- label vector branch ----------------
__global__ __launch_bounds__(256) void lv_kernel(const float* __restrict__ l, const float* __restrict__ W8,
                                                 const float* __restrict__ g8, const float* __restrict__ b8,
                                                 float* __restrict__ lv) {
  __shared__ float raw[4][64];
  int tid = threadIdx.x;
  {
    int b = tid / 64, o = tid % 64;
    float s = 0.f;
    for (int i = 0; i < 16; ++i) s += W8[o*16+i]*l[b*16+i];
    raw[b][o] = s;
  }
  __syncthreads();
  if (tid < 64) {
    int o = tid;
    float m = (raw[0][o]+raw[1][o]+raw[2][o]+raw[3][o])*0.25f;
    float v = 0.f;
    for (int b = 0; b < 4; ++b) { float d = raw[b][o]-m; v += d*d; }
    v *= 0.25f;
    float sc = g8[o]/sqrtf(v + BEPS);
    for (int b = 0; b < 4; ++b) {
      float y = sc*(raw[b][o]-m) + b8[o];
      lv[b*64+o] = leaky(y);
    }
  }
}

// ---------------- bias9 ----------------
__global__ __launch_bounds__(256) void bias9_kernel(const float* __restrict__ hmax, const float* __restrict__ lv,
                                                    const float* __restrict__ W9, float* __restrict__ bias9) {
  int i = blockIdx.x*256 + threadIdx.x;
  if (i >= 4*512) return;
  int b = i >> 9, o = i & 511;
  const float* wr = &W9[(size_t)o*1216];
  float s = 0.f;
  for (int c = 0; c < 1024; ++c) s += hmax[b*1024+c]*wr[c];
  for (int c = 0; c < 64; ++c) s += lv[b*64+c]*wr[1024+c];
  bias9[i] = s;
}

// ---------------- final transpose ----------------
__global__ __launch_bounds__(256) void out_kernel(const float* __restrict__ h5, float* __restrict__ out) {
  int i = blockIdx.x*256 + threadIdx.x;
  if (i >= NB*50*NP) return;
  int n = i % NP; int t = i / NP; int o = t % 50; int b = t / 50;
  out[i] = h5[((size_t)(b*NP+n))*50 + o];
}

// ================= host side =================
extern "C" void kernel_launch(void* const* d_in, const int* in_sizes, int n_in,
                              void* d_out, int out_size, void* d_ws, size_t ws_size,
                              hipStream_t stream) {
  const float* x   = (const float*)d_in[0];
  const float* l   = (const float*)d_in[1];
  const float* W3  = (const float*)d_in[2];
  const float* W4  = (const float*)d_in[3];
  const float* W5  = (const float*)d_in[4];
  const float* W6  = (const float*)d_in[5];
  const float* W7  = (const float*)d_in[6];
  const float* W8  = (const float*)d_in[7];
  const float* W9  = (const float*)d_in[8];
  const float* W10 = (const float*)d_in[9];
  const float* W11 = (const float*)d_in[10];
  const float* W12 = (const float*)d_in[11];
  const float* g3 = (const float*)d_in[12], *b3 = (const float*)d_in[13];
  const float* g4 = (const float*)d_in[14], *b4 = (const float*)d_in[15];
  const float* g5 = (const float*)d_in[16], *b5 = (const float*)d_in[17];
  const float* g6 = (const float*)d_in[18], *b6 = (const float*)d_in[19];
  const float* g7 = (const float*)d_in[20], *b7 = (const float*)d_in[21];
  const float* g8 = (const float*)d_in[22], *b8 = (const float*)d_in[23];
  const float* g9 = (const float*)d_in[24], *b9 = (const float*)d_in[25];
  const float* g10 = (const float*)d_in[26], *b10 = (const float*)d_in[27];
  const float* g11 = (const float*)d_in[28], *b11 = (const float*)d_in[29];
  (void)in_sizes; (void)n_in;

  constexpr size_t OFF_IDX1 = 0;
  constexpr size_t OFF_IDX2 = OFF_IDX1 + (size_t)NB*NP*KNN*4;
  constexpr size_t OFF_RC   = OFF_IDX2 + (size_t)NB*NP*KNN*4;
  constexpr size_t OFF_DRC  = OFF_RC   + (size_t)NB*NP*64*4;
  constexpr size_t OFF_XX   = OFF_DRC  + (size_t)NB*NP*64*4;
  constexpr size_t OFF_SLOT = OFF_XX   + (size_t)NB*NP*4;
  constexpr size_t OFF_ST3  = OFF_SLOT + (size_t)NSLOT*128*8;
  constexpr size_t OFF_ST4  = OFF_ST3 + 128*8;
  constexpr size_t OFF_ST5  = OFF_ST4 + 128*8;
  constexpr size_t OFF_ST6  = OFF_ST5 + 128*8;
  constexpr size_t OFF_STH  = OFF_ST6 + 128*8;
  constexpr size_t OFF_HMAX = OFF_STH + 2*1024*8;
  constexpr size_t OFF_LV   = OFF_HMAX + 4*1024*4;
  constexpr size_t OFF_B9   = OFF_LV + 4096;
  constexpr size_t OFF_PMAX = OFF_B9 + 4*512*4;
  constexpr size_t OFF_ALLF = OFF_PMAX + (size_t)NB*CMCH*1024*4;
  constexpr size_t OFF_H1   = OFF_ALLF + (size_t)NB*NP*128*4;
  constexpr size_t SZ_H1    = (size_t)NB*NP*1024*4;
  constexpr size_t OFF_END  = OFF_H1 + SZ_H1;
  constexpr size_t OFF_H2 = OFF_H1;
  constexpr size_t OFF_H3 = OFF_H2 + (size_t)NB*NP*512*4;
  constexpr size_t OFF_H4 = OFF_H3 + (size_t)NB*NP*256*4;
  constexpr size_t OFF_H5 = OFF_H4 + (size_t)NB*NP*128*4;
  static_assert(OFF_H5 + (size_t)NB*NP*50*4 <= OFF_END, "h alias overflow");
  // fast-path y buffer
  constexpr size_t OFF_Y   = OFF_END;
  constexpr size_t SZ_Y    = (size_t)NB*NP*KNN*64*4;   // 83,886,080
  constexpr size_t OFF_FAST_END = OFF_Y + SZ_Y;

  if (ws_size < OFF_END) {
    canary_kernel<<<(out_size + 255)/256, 256, 0, stream>>>((float*)d_out, out_size, (float)(ws_size >> 20));
    return;
  }
  const bool FAST = (ws_size >= OFF_FAST_END);

  char* ws = (char*)d_ws;
  int*    idx1  = (int*)(ws + OFF_IDX1);
  int*    idx2  = (int*)(ws + OFF_IDX2);
  float*  rc    = (float*)(ws + OFF_RC);
  float*  drc   = (float*)(ws + OFF_DRC);
  float*  xx2   = (float*)(ws + OFF_XX);
  double* slots = (double*)(ws + OFF_SLOT);
  double* st3s  = (double*)(ws + OFF_ST3);
  double* st4s  = (double*)(ws + OFF_ST4);
  double* st5s  = (double*)(ws + OFF_ST5);
  double* st6s  = (double*)(ws + OFF_ST6);
  double* sth   = (double*)(ws + OFF_STH);
  float*  hmaxb = (float*)(ws + OFF_HMAX);
  float*  lvb   = (float*)(ws + OFF_LV);
  float*  bias9 = (float*)(ws + OFF_B9);
  float*  pmaxb = (float*)(ws + OFF_PMAX);
  float*  allf  = (float*)(ws + OFF_ALLF);
  float*  h1    = (float*)(ws + OFF_H1);
  float*  h2    = (float*)(ws + OFF_H2);
  float*  h3    = (float*)(ws + OFF_H3);
  float*  h4    = (float*)(ws + OFF_H4);
  float*  h5    = (float*)(ws + OFF_H5);
  float*  ybuf  = (float*)(ws + OFF_Y);

  dim3 gridNP(NP, NB);
  dim3 gridKNN2(NP/2, NB);
  const size_t slotBytes = (size_t)NSLOT*128*8;
  const double INV_M2 = 1.0/8192.0;

  // ---- stage 1 ----
  knn3_kernel<<<gridKNN2, 256, 0, stream>>>(x, idx1);
  hipMemsetAsync(slots, 0, slotBytes, stream);
  s1a_kernel<<<gridNP, 256, 0, stream>>>(x, idx1, W3, slots, FAST ? ybuf : h1);
  redstats_kernel<<<1, 128, 0, stream>>>(slots, st3s);
  hipMemsetAsync(slots, 0, slotBytes, stream);
  mid_kernel<<<gridNP, 256, 0, stream>>>(FAST ? ybuf : h1, W4, st3s, g3, b3, slots);
  redstats_kernel<<<1, 128, 0, stream>>>(slots, st4s);
  maxk_bn_kernel<<<(NB*NP*64 + 255)/256, 256, 0, stream>>>(FAST ? ybuf : h1, st4s, g4, b4, rc);

  // ---- stage 2 ----
  xx64_kernel<<<(NB*NP + 255)/256, 256, 0, stream>>>(rc, xx2);
  knn64_kernel<<<gridKNN2, 256, 0, stream>>>(rc, xx2, idx2);
  hipMemsetAsync(slots, 0, slotBytes, stream);
  s2a_kernel<<<gridNP, 256, 0, stream>>>(rc, idx2, W5, slots, FAST ? ybuf : h1);
  redstats_kernel<<<1, 128, 0, stream>>>(slots, st5s);
  hipMemsetAsync(slots, 0, slotBytes, stream);
  mid_kernel<<<gridNP, 256, 0, stream>>>(FAST ? ybuf : h1, W6, st5s, g5, b5, slots);
  redstats_kernel<<<1, 128, 0, stream>>>(slots, st6s);
  maxk_bn_kernel<<<(NB*NP*64 + 255)/256, 256, 0, stream>>>(FAST ? ybuf : h1, st6s, g6, b6, drc);

  // ---- stage 3: global head ----
  allf_kernel<<<(NB*NP*128 + 255)/256, 256, 0, stream>>>(rc, drc, allf);
  gemm_kernel<<<dim3(1024/GBN, 8192/GBM), 256, 0, stream>>>(allf, W7, h1, 8192, 1024, 128, 128, 0, nullptr);
  hipMemsetAsync(sth, 0, 2*1024*8, stream);
  colstats_kernel<<<128, 256, 0, stream>>>(h1, 8192, 1024, 64, sth);
  bnapply_kernel<<<(unsigned)(((size_t)8192*1024 + 255)/256), 256, 0, stream>>>(h1, sth, g7, b7, INV_M2, 1023, (size_t)8192*1024);
  colmax_part_kernel<<<(NB*CMCH*1024 + 255)/256, 256, 0, stream>>>(h1, 1024, pmaxb);
  colmax_fin_kernel<<<(NB*1024 + 255)/256, 256, 0, stream>>>(pmaxb, 1024, hmaxb);
  lv_kernel<<<1, 256, 0, stream>>>(l, W8, g8, b8, lvb);
  bias9_kernel<<<8, 256, 0, stream>>>(hmaxb, lvb, W9, bias9);

  gemm_kernel<<<dim3(512/GBN, 8192/GBM), 256, 0, stream>>>(allf, W9, h2, 8192, 512, 128, 1216, 1088, bias9);
  hipMemsetAsync(sth, 0, 2*512*8, stream);
  colstats_kernel<<<128, 256, 0, stream>>>(h2, 8192, 512, 64, sth);
  bnapply_kernel<<<(unsigned)(((size_t)8192*512 + 255)/256), 256, 0, stream>>>(h2, sth, g9, b9, INV_M2, 511, (size_t)8192*512);

  gemm_kernel<<<dim3(256/GBN, 8192/GBM), 256, 0, stream>>>(h2, W10, h3, 8192, 256, 512, 512, 0, nullptr);
  hipMemsetAsync(sth, 0, 2*256*8, stream);
  colstats_kernel<<<128, 256, 0, stream>>>(h3, 8192, 256, 64, sth);
  bnapply_kernel<<<(unsigned)(((size_t)8192*256 + 255)/256), 256, 0, stream>>>(h3, sth, g10, b10, INV_M2, 255, (size_t)8192*256);

  gemm_kernel<<<dim3(128/GBN, 8192/GBM), 256, 0, stream>>>(h3, W11, h4, 8192, 128, 256, 256, 0, nullptr);
  hipMemsetAsync(sth, 0, 2*128*8, stream);
  colstats_kernel<<<128, 256, 0, stream>>>(h4, 8192, 128, 64, sth);
  bnapply_kernel<<<(unsigned)(((size_t)8192*128 + 255)/256), 256, 0, stream>>>(h4, sth, g11, b11, INV_M2, 127, (size_t)8192*128);

  gemm_kernel<<<dim3(1, 8192/GBM), 256, 0, stream>>>(h4, W12, h5, 8192, 50, 128, 128, 0, nullptr);
  out_kernel<<<(NB*50*NP + 255)/256, 256, 0, stream>>>(h5, (float*)d_out);
}